// Round 7
// baseline (179.345 us; speedup 1.0000x reference)
//
#include <hip/hip_runtime.h>
#include <math.h>

#define G_MAX 512   // LDS capacity for GT boxes; setup uses G=300
#define SPLIT 4     // threads per anchor (g-loop split)

typedef float v2f __attribute__((ext_vector_type(2)));

__device__ __forceinline__ float waveSum(float v) {
#pragma unroll
  for (int o = 32; o > 0; o >>= 1) v += __shfl_down(v, o, 64);
  return v;
}

// smooth-L1 with sigma=3 (s2=9)
__device__ __forceinline__ float huber9(float x) {
  float ax = fabsf(x);
  return (ax < (1.0f / 9.0f)) ? 4.5f * x * x : ax - (0.5f / 9.0f);
}

// Exact IoU in the reference's op order. g = (x0, y0, x1+1, y1+1)
__device__ __forceinline__ float iouExact(float bx0, float by0, float bx1, float by1,
                                          float areab, float4 g, float areag) {
  float gx1 = g.z - 1.0f, gy1 = g.w - 1.0f;  // exact inverse of the staged +1
  float iw = fminf(bx1, gx1) - fmaxf(bx0, g.x) + 1.0f;
  float ih = fminf(by1, gy1) - fmaxf(by0, g.y) + 1.0f;
  float inter = fmaxf(iw, 0.f) * fmaxf(ih, 0.f);
  float uni = areab + areag - inter;
  return inter / fmaxf(uni, 1.0f);
}

// Two-g packed inverse-key (see R5/R6 rationale; per-half IEEE-identical to
// the scalar version, so the exactness argument is unchanged):
//   key = (areaB+areaG)*rcp(inter), inter = max(iw,0)*ih (one-clamp: negative
//   ih sends the key into the >=0x80000000 "zero-overlap" class whose internal
//   order is output-invariant). argmax iou == argmin key as uint. Low 9 bits
//   carry g (min-ties -> smallest g = jax stable semantics).
// sub/mul/add are float2 ext-vector ops -> v_pk_{add,mul}_f32 (dual-rate fp32);
// min/max/rcp have no packed form and stay scalar.
__device__ __forceinline__ void packKey2(float x0, float y0, float x1p, float y1p,
                                         float area, const float4 gbA, const float4 gbB,
                                         v2f ga2, uint32_t g,
                                         uint32_t& k0, uint32_t& k1) {
  v2f mnx, mxx, mny, mxy;
  mnx.x = fminf(x1p, gbA.z); mnx.y = fminf(x1p, gbB.z);
  mxx.x = fmaxf(x0, gbA.x);  mxx.y = fmaxf(x0, gbB.x);
  mny.x = fminf(y1p, gbA.w); mny.y = fminf(y1p, gbB.w);
  mxy.x = fmaxf(y0, gbA.y);  mxy.y = fmaxf(y0, gbB.y);
  v2f iw = mnx - mxx;          // v_pk_add_f32 (neg)
  v2f ih = mny - mxy;          // v_pk_add_f32 (neg)
  v2f iwc; iwc.x = fmaxf(iw.x, 0.f); iwc.y = fmaxf(iw.y, 0.f);
  v2f inter = iwc * ih;        // v_pk_mul_f32
  v2f S = ga2 + area;          // v_pk_add_f32 (splat)
  v2f r; r.x = __builtin_amdgcn_rcpf(inter.x); r.y = __builtin_amdgcn_rcpf(inter.y);
  v2f key = S * r;             // v_pk_mul_f32
  uint32_t b0 = __float_as_uint(key.x), b1 = __float_as_uint(key.y);
  k0 = (b0 & 0xFFFFFE00u) | (g & 0x1FFu);         // v_bfi_b32 pattern
  k1 = (b1 & 0xFFFFFE00u) | ((g + 1u) & 0x1FFu);  // v_bfi_b32 pattern
}

__global__ __launch_bounds__(256) void retina_main(
    const float* __restrict__ pred_cls,   // (n, A, 2)
    const float* __restrict__ rpn_num,    // (n, A, 2)
    const float* __restrict__ pred_reg,   // (n, A, 8)
    const float* __restrict__ anchors,    // (A, 4)
    const float* __restrict__ rpn_iou,    // (n, A, 2)
    const float* __restrict__ boxes,      // (n, G, 5)
    int A, int G, int totalBlocks,
    double* __restrict__ acc,             // 7 accumulators, stride 16 doubles
    unsigned int* __restrict__ cnt,       // ticket counter (zeroed)
    float* __restrict__ out)              // 4 floats
{
  __shared__ float4 sBox[G_MAX];      // x0, y0, x1+1, y1+1
  __shared__ v2f sA2[G_MAX / 2];      // areas, pairs (1e30 for invalid/dummy)
  __shared__ float sRed[4][7];
  __shared__ int sLast;

  float* sA = (float*)sA2;

  const int img = blockIdx.y;
  const int seg = threadIdx.x & (SPLIT - 1);
  const int al  = threadIdx.x >> 2;          // anchor-local 0..63
  const int i   = blockIdx.x * 64 + al;
  const int ic  = (i < A) ? i : (A - 1);

  const int len  = (((G + SPLIT - 1) / SPLIT) + 1) & ~1;  // even per-seg length
  const int padG = len * SPLIT;              // <= G_MAX

  // stage GT boxes (pad range with inert dummies: area=1e30)
  const float* gtb = boxes + (size_t)img * G * 5;
  for (int g = threadIdx.x; g < padG; g += 256) {
    if (g < G) {
      float x0 = gtb[g * 5 + 0], y0 = gtb[g * 5 + 1];
      float x1 = gtb[g * 5 + 2], y1 = gtb[g * 5 + 3];
      float lb = gtb[g * 5 + 4];
      sBox[g] = make_float4(x0, y0, x1 + 1.0f, y1 + 1.0f);
      sA[g] = (lb != -1.0f) ? (x1 - x0 + 1.0f) * (y1 - y0 + 1.0f) : 1e30f;
    } else {
      sBox[g] = make_float4(0.f, 0.f, 1.f, 1.f);
      sA[g] = 1e30f;
    }
  }
  __syncthreads();

  float t_cls = 0.f, t_bbox = 0.f, t_iou = 0.f, t_num = 0.f;
  float t_npos = 0.f, t_nfg = 0.f, t_ncnt = 0.f;

  const float BBOX_CLIP = 4.1351666f;  // log(1000/16)

  // per-anchor data (4 lanes share one anchor; redundant loads hit L1)
  float ax0 = anchors[ic * 4 + 0], ay0 = anchors[ic * 4 + 1];
  float ax1 = anchors[ic * 4 + 2], ay1 = anchors[ic * 4 + 3];
  float aw = ax1 - ax0 + 1.0f, ah = ay1 - ay0 + 1.0f;
  float areaa = aw * ah;
  float acx = ax0 + 0.5f * aw, acy = ay0 + 0.5f * ah;
  float ax1p = ax1 + 1.0f, ay1p = ay1 + 1.0f;

  const float* dp = pred_reg + ((size_t)img * A + ic) * 8;
  float d0 = dp[0], d1 = dp[1], d2 = dp[2], d3 = dp[3];
  float d4 = dp[4], d5 = dp[5], d6 = dp[6], d7 = dp[7];

  // epilogue-only inputs: issue early (exec-masked to seg 0) to hide latency
  float pcv0 = 0.f, pcv1 = 0.f, riv0 = 0.f, riv1 = 0.f, sn0 = 0.f, sn1 = 0.f;
  if (seg == 0) {
    const float* pc = pred_cls + ((size_t)img * A + ic) * 2;
    pcv0 = pc[0]; pcv1 = pc[1];
    const float* ri = rpn_iou + ((size_t)img * A + ic) * 2;
    riv0 = ri[0]; riv1 = ri[1];
    const float* sp = rpn_num + ((size_t)img * A + ic) * 2;
    sn0 = sp[0]; sn1 = sp[1];
  }

  // decode predicted boxes
  float p0cx = acx + d0 * aw, p0cy = acy + d1 * ah;
  float p0w = aw * expf(fminf(d2, BBOX_CLIP));
  float p0h = ah * expf(fminf(d3, BBOX_CLIP));
  float b0x0 = p0cx - 0.5f * p0w, b0y0 = p0cy - 0.5f * p0h;
  float b0x1 = p0cx + 0.5f * p0w, b0y1 = p0cy + 0.5f * p0h;
  float area0 = (b0x1 - b0x0 + 1.0f) * (b0y1 - b0y0 + 1.0f);
  float b0x1p = b0x1 + 1.0f, b0y1p = b0y1 + 1.0f;

  float p1cx = acx + d4 * aw, p1cy = acy + d5 * ah;
  float p1w = aw * expf(fminf(d6, BBOX_CLIP));
  float p1h = ah * expf(fminf(d7, BBOX_CLIP));
  float b1x0 = p1cx - 0.5f * p1w, b1y0 = p1cy - 0.5f * p1h;
  float b1x1 = p1cx + 0.5f * p1w, b1y1 = p1cy + 0.5f * p1h;
  float area1 = (b1x1 - b1x0 + 1.0f) * (b1y1 - b1y0 + 1.0f);
  float b1x1p = b1x1 + 1.0f, b1y1p = b1y1 + 1.0f;

  // min-trackers over inverse keys (merge-associative)
  uint32_t an1 = 0xFFFFFFFFu, an2 = 0xFFFFFFFFu;   // anchor-vs-gt best/2nd
  uint32_t am  = 0xFFFFFFFFu;                      // decoded box 0 best
  uint32_t bk1 = 0xFFFFFFFFu, bk2 = 0xFFFFFFFFu;   // decoded box 1 best/2nd

  int g = seg * len;  // even (len is even)
#pragma unroll 6
  for (int t = 0; t < len; t += 2, g += 2) {
    float4 gbA = sBox[g];
    float4 gbB = sBox[g + 1];
    v2f ga2 = sA2[g >> 1];           // ds_read_b64
    uint32_t gu = (uint32_t)g;
    {
      uint32_t k0, k1;
      packKey2(ax0, ay0, ax1p, ay1p, areaa, gbA, gbB, ga2, gu, k0, k1);
      uint32_t lo = min(k0, k1), hi0 = max(k0, k1);
      uint32_t m1 = max(an1, lo);
      an2 = min(an2, min(hi0, m1));
      an1 = min(an1, lo);
    }
    {
      uint32_t k0, k1;
      packKey2(b0x0, b0y0, b0x1p, b0y1p, area0, gbA, gbB, ga2, gu, k0, k1);
      am = min(am, min(k0, k1));
    }
    {
      uint32_t k0, k1;
      packKey2(b1x0, b1y0, b1x1p, b1y1p, area1, gbA, gbB, ga2, gu, k0, k1);
      uint32_t lo = min(k0, k1), hi0 = max(k0, k1);
      uint32_t m1 = max(bk1, lo);
      bk2 = min(bk2, min(hi0, m1));
      bk1 = min(bk1, lo);
    }
  }

  // butterfly merge across the 4 lanes of this anchor
#pragma unroll
  for (int m = 1; m <= 2; m <<= 1) {
    uint32_t o1 = (uint32_t)__shfl_xor((int)an1, m, 64);
    uint32_t o2 = (uint32_t)__shfl_xor((int)an2, m, 64);
    uint32_t hi = max(an1, o1);
    an1 = min(an1, o1);
    an2 = min(min(an2, o2), hi);

    am = min(am, (uint32_t)__shfl_xor((int)am, m, 64));

    uint32_t q1 = (uint32_t)__shfl_xor((int)bk1, m, 64);
    uint32_t q2 = (uint32_t)__shfl_xor((int)bk2, m, 64);
    uint32_t hib = max(bk1, q1);
    bk1 = min(bk1, q1);
    bk2 = min(min(bk2, q2), hib);
  }

  if (seg == 0 && i < A) {
    // winning indices; clamp defensively to the initialized LDS range
    int pg1 = padG - 1;
    int i0 = min((int)(an1 & 0x1FFu), pg1);
    int i1 = min((int)(an2 & 0x1FFu), pg1);
    int ai = min((int)(am  & 0x1FFu), pg1);
    int bi = min((int)(bk1 & 0x1FFu), pg1);
    int bi2= min((int)(bk2 & 0x1FFu), pg1);

    // exact recompute of winning values (reference op order, explicit validity)
    float4 g0 = sBox[i0]; float a0 = sA[i0]; bool val0 = a0 < 1e29f;
    float v0 = val0 ? iouExact(ax0, ay0, ax1, ay1, areaa, g0, a0) : -1.0f;
    float4 g1 = sBox[i1]; float a1 = sA[i1]; bool val1 = a1 < 1e29f;
    float v1 = val1 ? iouExact(ax0, ay0, ax1, ay1, areaa, g1, a1) : -1.0f;
    float4 ga4 = sBox[ai]; float aav = sA[ai];
    float aval = (aav < 1e29f) ? iouExact(b0x0, b0y0, b0x1, b0y1, area0, ga4, aav) : 0.0f;
    int bIdx = (ai == bi) ? bi2 : bi;  // b with b[ai] zeroed, then argmax
    float4 gb4 = sBox[bIdx]; float abv = sA[bIdx];
    float bval = (abv < 1e29f) ? iouExact(b1x0, b1y0, b1x1, b1y1, area1, gb4, abv) : 0.0f;

    // labels: >=0.5 -> 1, <0.4 -> 0, else -1
    float la  = (v0 >= 0.5f) ? 1.0f : ((v0 < 0.4f) ? 0.0f : -1.0f);
    float lbv = (v1 >= 0.5f) ? 1.0f : ((v1 < 0.4f) ? 0.0f : -1.0f);
    float lab0 = la;
    float lab1 = lbv - (((la == 0.0f) && (lbv != 0.0f)) ? 1.0f : 0.0f);

    // ---- focal classification loss ----
    {
      float p = pcv0;
      if (lab0 != -1.0f) {
        float l = (lab0 == 1.0f)
                      ? 0.25f * (1.0f - p) * (1.0f - p) * logf(p)
                      : 0.75f * p * p * logf(1.0f - p);
        t_cls -= l;
      }
      if (lab0 > 0.f) t_npos += 1.f;
      float q = pcv1;
      if (lab1 != -1.0f) {
        float l = (lab1 == 1.0f)
                      ? 0.25f * (1.0f - q) * (1.0f - q) * logf(q)
                      : 0.75f * q * q * logf(1.0f - q);
        t_cls -= l;
      }
      if (lab1 > 0.f) t_npos += 1.f;
    }

    bool fg0 = (lab0 != 0.0f) && (lab0 != -1.0f);
    bool fg1 = (lab1 != 0.0f) && (lab1 != -1.0f);

    // fast reciprocals for the bbox-target divides (rel err ~1e-7, harmless)
    float raw = __builtin_amdgcn_rcpf(aw), rah = __builtin_amdgcn_rcpf(ah);

    // ---- bbox smooth-L1 vs bbox_transform(anchor, matched gt) ----
    if (fg0) {
      float mx1 = g0.z - 1.0f, my1 = g0.w - 1.0f;
      float gw = mx1 - g0.x + 1.0f, gh = my1 - g0.y + 1.0f;
      float gcx = g0.x + 0.5f * gw, gcy = g0.y + 0.5f * gh;
      float t0 = (gcx - acx) * raw, t1v = (gcy - acy) * rah;
      float t2 = logf(gw * raw), t3 = logf(gh * rah);
      t_bbox += huber9(d0 - t0) + huber9(d1 - t1v) + huber9(d2 - t2) + huber9(d3 - t3);
      t_nfg += 1.f;
    }
    if (fg1) {
      float mx1 = g1.z - 1.0f, my1 = g1.w - 1.0f;
      float gw = mx1 - g1.x + 1.0f, gh = my1 - g1.y + 1.0f;
      float gcx = g1.x + 0.5f * gw, gcy = g1.y + 0.5f * gh;
      float t0 = (gcx - acx) * raw, t1v = (gcy - acy) * rah;
      float t2 = logf(gw * raw), t3 = logf(gh * rah);
      t_bbox += huber9(d4 - t0) + huber9(d5 - t1v) + huber9(d6 - t2) + huber9(d7 - t3);
      t_nfg += 1.f;
    }

    // ---- IoU L1 loss ----
    if (fg0) t_iou += fabsf(riv0 - aval);
    if (fg1) t_iou += fabsf(riv1 - fmaxf(bval, 0.0f));

    // ---- num softmax loss ----
    {
      int nl = ((lab0 > 0.f) ? 1 : 0) + ((lab1 > 0.f) ? 1 : 0) - 1;
      if (nl != -1) {
        float m = fmaxf(sn0, sn1);
        float lse = m + logf(expf(sn0 - m) + expf(sn1 - m));
        float picked = ((nl == 0) ? sn0 : sn1) - lse;
        t_num -= picked;
        t_ncnt += 1.f;
      }
    }
  }

  // block reduction: wave shuffle -> LDS -> one double atomic per scalar
  float vals[7] = {t_cls, t_bbox, t_iou, t_num, t_npos, t_nfg, t_ncnt};
  int lane = threadIdx.x & 63;
  int wid = threadIdx.x >> 6;
#pragma unroll
  for (int k = 0; k < 7; ++k) {
    float s = waveSum(vals[k]);
    if (lane == 0) sRed[wid][k] = s;
  }
  __syncthreads();
  if (threadIdx.x < 7) {
    double s = (double)sRed[0][threadIdx.x] + (double)sRed[1][threadIdx.x] +
               (double)sRed[2][threadIdx.x] + (double)sRed[3][threadIdx.x];
    atomicAdd(&acc[threadIdx.x * 16], s);  // 128 B apart, device-scope
    __threadfence();                       // release our adds device-wide
  }
  __syncthreads();
  if (threadIdx.x == 0) {
    unsigned int old = atomicAdd(cnt, 1u); // ticket; device-scope
    sLast = (old == (unsigned int)(totalBlocks - 1)) ? 1 : 0;
  }
  __syncthreads();

  // last block finalizes: read accumulators through the atomic domain
  if (sLast && threadIdx.x == 0) {
    __threadfence();
    double cls  = atomicAdd(&acc[0 * 16], 0.0);
    double bbox = atomicAdd(&acc[1 * 16], 0.0);
    double iou  = atomicAdd(&acc[2 * 16], 0.0);
    double num  = atomicAdd(&acc[3 * 16], 0.0);
    double npos = atomicAdd(&acc[4 * 16], 0.0);
    double nfg  = atomicAdd(&acc[5 * 16], 0.0);
    double ncnt = atomicAdd(&acc[6 * 16], 0.0);
    double dpos = npos > 1.0 ? npos : 1.0;
    double dfg  = nfg  > 1.0 ? nfg  : 1.0;
    double dcnt = ncnt > 1.0 ? ncnt : 1.0;
    out[0] = (float)(cls / dpos);
    out[1] = (float)(2.0 * bbox / dfg);
    out[2] = (float)(2.0 * iou / dfg);
    out[3] = (float)(num / dcnt);
  }
}

extern "C" void kernel_launch(void* const* d_in, const int* in_sizes, int n_in,
                              void* d_out, int out_size, void* d_ws, size_t ws_size,
                              hipStream_t stream) {
  const float* pred_cls = (const float*)d_in[0];
  const float* rpn_num  = (const float*)d_in[1];
  const float* pred_reg = (const float*)d_in[2];
  const float* anchors  = (const float*)d_in[3];
  const float* rpn_iou  = (const float*)d_in[4];
  const float* boxes    = (const float*)d_in[5];
  // d_in[6] = im_info: unused by the reference math

  int A = in_sizes[3] / 4;
  int n = in_sizes[0] / (2 * A);
  int G = in_sizes[5] / (5 * n);

  double* acc = (double*)d_ws;                       // 7 x stride-16 doubles
  unsigned int* cnt = (unsigned int*)((char*)d_ws + 7 * 16 * sizeof(double));
  hipMemsetAsync(d_ws, 0, 7 * 16 * sizeof(double) + sizeof(unsigned int), stream);

  int nBx = (A + 63) / 64;
  int totalBlocks = nBx * n;
  dim3 grid(nBx, n, 1);  // 64 anchors/block x SPLIT=4 lanes
  retina_main<<<grid, dim3(256, 1, 1), 0, stream>>>(
      pred_cls, rpn_num, pred_reg, anchors, rpn_iou, boxes,
      A, G, totalBlocks, acc, cnt, (float*)d_out);
}